// Round 9
// baseline (227.625 us; speedup 1.0000x reference)
//
#include <hip/hip_runtime.h>

// LSTM: T=512, B=4096, IN=1, H=12.
// R19 = R15's PASSING structure (gate-pair split, 2 cells/wave, 2 waves/
// SIMD) with the marriage moved from ds_swizzle (LDS pipe, ~100+ cyc on
// the chain - R15's killer) to v_permlane32_swap_b32 via its BUILTIN.
//
// Why this is the right lever (R18 post-mortem): residency theory is
// dead (VGPR 64->132, dur unchanged). Measured map: R12 = 122.5us is the
// 1-wave floor (574 cyc/step = 293 busy + 281 stall); R15's per-wave
// issue was 275 cyc, so 2 waves want 550 < 574 -> the split WINS iff
// marriage is VALU-latency. permlane32_swap is full-rate VALU cross-lane
// (gfx950-new). R14's asm version failed because "+v"(a),"+v"(b) with
// a==b lets the compiler alias both operands into one VGPR; the builtin
// carries true semantics (returns BOTH outputs).
// Orientation-robust: probe r = swap(lane,lane); one output is the
// lo-half splat, the other the hi-half splat (either order); per-lane
// predicate selx = (r.x == lane^32) makes partner(v) = selx ? r.x : r.y
// correct under either orientation. 1 permlane + 1 cndmask per exchange.
//
// Structure (R15-proven, only lane mapping + exchange changed):
//  - half = lane>>5 (0:(i,f), 1:(g,o)), cell = (lane>>4)&1, j = lane&15
//    (12..15 finite clones). Partner = lane^32 = same cell/j, other half.
//  - h in registers, replicated per 16-lane row; gather via R10-proven
//    15x DPP row_ror + per-source-slot pair-weight tables (probed
//    direction, clone sources zero-gated). ONE pk-pair chain per lane:
//    16 pkfma + init. NO LDS anywhere on the recurrence chain.
//  - trans shared across halves: E0,E1 (gates), r0,r1 (sigmoids), Ec,rc
//    (cell tanh) = 3 exp2 + 3 rcp total (vs 8-10 in 1-wave forms).
//  - 3 exchanges/step: tgS->half0, so->half0, hn refresh->half1. Mirror
//    values garbage-but-finite (R13/R15-proven analysis), refreshed
//    before any read.
//  - fc: ring ror-reduce DELAYED one step (R11-proven) split into the
//    two exp2->rcp windows; fake t=0 store aliases out[0], overwritten;
//    epilogue flushes t=511.
//  - X staged per chunk (float2) to LDS [cell][time] XPAD=68; xq b128
//    one 4-step group ahead.
// Budget: per-wave issue ~250-265, chain ~180-210 all-VALU; wall ~
// max(2*issue, chain) ~ 500-540 cyc/step. Predict 104-115us,
// VALUBusy 78-88%, Occ ~19-21%, conflicts 0.

#define TT    512
#define NB    4096
#define HH    12
#define RPW   2      // cells per wave
#define CHUNK 64     // X staging chunk; TT % CHUNK == 0
#define XPAD  68     // padded x row stride (floats)

typedef float v2f __attribute__((ext_vector_type(2)));
typedef unsigned int u2v __attribute__((ext_vector_type(2)));

static __device__ __forceinline__ v2f pkfma(v2f a, v2f b, v2f c) {
#if __has_builtin(__builtin_elementwise_fma)
    return __builtin_elementwise_fma(a, b, c);
#else
    v2f r; r.x = fmaf(a.x, b.x, c.x); r.y = fmaf(a.y, b.y, c.y); return r;
#endif
}
static __device__ __forceinline__ v2f splat2(float s) { v2f r; r.x = s; r.y = s; return r; }

#define SNEG   (-1.44269504088896340736f)   // sigmoid pre-scale: -log2(e)
#define SPOS   ( 2.88539008177792681472f)   // tanh pre-scale: +2*log2(e)
#define M2SPOS (-5.77078016355585362944f)   // -2*SPOS

#define ROR(r) (0x120 + (r))                // DPP ctrl: row_ror:r

__global__ __launch_bounds__(64)
__attribute__((amdgpu_waves_per_eu(2, 2)))
void lstm_fused(const float* __restrict__ X,
                const float* __restrict__ W_ih,
                const float* __restrict__ W_hh,
                const float* __restrict__ b_ih,
                const float* __restrict__ b_hh,
                const float* __restrict__ fc_w,
                const float* __restrict__ fc_b,
                float* __restrict__ out)
{
    __shared__ __align__(16) float xchunk[RPW][XPAD]; // [cell][time]

    const int lane = threadIdx.x;          // 0..63
    const int half = lane >> 5;            // 0: (i,f)  1: (g,o)
    const int cell = (lane >> 4) & 1;      // cell within wave
    const int j    = lane & 15;            // 0..11 real, 12..15 clones
    const int cellbase = blockIdx.x * RPW;
    const int gcell = cellbase + cell;

    // ---- probe permlane32_swap orientation: per-lane predicate selx
#if __has_builtin(__builtin_amdgcn_permlane32_swap)
    bool selx;
    {
        const u2v pr = __builtin_amdgcn_permlane32_swap(
            (unsigned)lane, (unsigned)lane, false, false);
        selx = (pr.x == (unsigned)(lane ^ 32));
    }
#define PSWAP(v) ({                                                       \
        const u2v r_ = __builtin_amdgcn_permlane32_swap(                  \
            (unsigned)__float_as_int(v), (unsigned)__float_as_int(v),     \
            false, false);                                                \
        __int_as_float((int)(selx ? r_.x : r_.y)); })
#else
    const int paddr = (lane ^ 32) << 2;    // ds_bpermute fallback (64-lane)
#define PSWAP(v) __int_as_float(__builtin_amdgcn_ds_bpermute(paddr, __float_as_int(v)))
#endif

    // ---- probe DPP ror direction: sid[r] = within-row source lane of ror r
    int sid[16];
    sid[0] = j;
#define PROBE(r) sid[r] = __builtin_amdgcn_update_dpp(0, j, ROR(r), 0xF, 0xF, true);
    PROBE(1)  PROBE(2)  PROBE(3)  PROBE(4)  PROBE(5)
    PROBE(6)  PROBE(7)  PROBE(8)  PROBE(9)  PROBE(10)
    PROBE(11) PROBE(12) PROBE(13) PROBE(14) PROBE(15)
#undef PROBE

    const int jc = (j < HH) ? j : (HH - 1);   // clamp clone lanes (finite)

    // ---- per-source-slot gate-PAIR weight tables (r=0 = local source).
    // half0: pair (i,f) both SNEG; half1: pair (g SPOS, o SNEG).
    const int   gA = (half ? 2 : 0) * HH + jc;
    const int   gB = (half ? 3 : 1) * HH + jc;
    const float sA = half ? SPOS : SNEG;
    const float* WA = W_hh + gA * HH;
    const float* WB = W_hh + gB * HH;
    v2f wU[16];
    #pragma unroll
    for (int r = 0; r < 16; ++r) {
        const int  s  = sid[r];
        const int  sc = (s < HH) ? s : (HH - 1);
        const float g = ((j >= HH) || (s < HH)) ? 1.0f : 0.0f;
        wU[r].x = g * sA   * WA[sc];
        wU[r].y = g * SNEG * WB[sc];
    }
    v2f wxv, bv;
    wxv.x = sA   * W_ih[gA];               // IN == 1, W_ih flat [48]
    wxv.y = SNEG * W_ih[gB];
    bv.x  = sA   * (b_ih[gA] + b_hh[gA]);
    bv.y  = SNEG * (b_ih[gB] + b_hh[gB]);

    const float fcb  = fc_b[0];
    const float fcwj = (j < HH) ? fc_w[j] : 0.0f;   // clones contribute 0

    float c2 = 0.0f;     // pre-scaled cell state SPOS*c (valid: half0 lanes)
    float hn = 0.0f;     // h[cell][j], replicated in both halves
    int hbits = 0;

    // delayed-output state (R11 trick)
    float pPend = 0.0f;
    unsigned offPrev = 0;
    float* const outp = out + gcell;

    // prefetch chunk 0 of X: X[t=lane][cellbase + 0..1]
    float2 gq = *(const float2*)(X + (size_t)lane * NB + cellbase);

    for (int tc = 0; tc < TT; tc += CHUNK) {
        xchunk[0][lane] = gq.x;            // cell0 row, time slot = lane
        xchunk[1][lane] = gq.y;            // cell1 row
        if (tc + CHUNK < TT)
            gq = *(const float2*)(X + (size_t)(tc + CHUNK + lane) * NB + cellbase);
        __builtin_amdgcn_wave_barrier();   // order staging vs xq reads

        float4 xq_next = *(const float4*)&xchunk[cell][0];

        for (int t4 = 0; t4 < CHUNK; t4 += 4) {
            const float4 xq = xq_next;                       // group t4
            const int nx = (t4 + 4 < CHUNK) ? (t4 + 4) : t4; // clamp tail
            xq_next = *(const float4*)&xchunk[cell][nx];
            const float xs[4] = {xq.x, xq.y, xq.z, xq.w};

            #pragma unroll
            for (int u = 0; u < 4; ++u) {
                // chain head: bias + x-proj, then local + 15 ror sources
                v2f aA = pkfma(splat2(xs[u]), wxv, bv);
                v2f aB; aB.x = 0.0f; aB.y = 0.0f;
                aA = pkfma(wU[0], splat2(hn), aA);   // local (r=0)
#define XR(r) { \
                const int hr_##r = __builtin_amdgcn_update_dpp(0, hbits, ROR(r), 0xF, 0xF, true); \
                const v2f hk = splat2(__int_as_float(hr_##r)); \
                if ((r) < 8) { aA = pkfma(wU[r], hk, aA); } \
                else         { aB = pkfma(wU[r], hk, aB); } }
                XR(1)  XR(2)  XR(3)  XR(4)  XR(5)
                XR(6)  XR(7)  XR(8)  XR(9)  XR(10)
                XR(11) XR(12) XR(13) XR(14) XR(15)
#undef XR
                const v2f a = aA + aB;               // v_pk_add_f32

                const float E0 = __builtin_amdgcn_exp2f(a.x);  // i | g
                const float E1 = __builtin_amdgcn_exp2f(a.y);  // f | o

                // delayed fc-reduce (prev step), first half: fills the
                // gate exp2->rcp window
                float p = pPend;
                p += __int_as_float(__builtin_amdgcn_update_dpp(0, __float_as_int(p), ROR(8), 0xF, 0xF, true));
                p += __int_as_float(__builtin_amdgcn_update_dpp(0, __float_as_int(p), ROR(4), 0xF, 0xF, true));

                const float r0 = __builtin_amdgcn_rcpf(1.0f + E0); // si | rg
                const float r1 = __builtin_amdgcn_rcpf(1.0f + E1); // sf | so
                const float t0 = fmaf(M2SPOS, r0, SPOS);           // -- | tgS

                // marriage across lane^32 (full-rate VALU permlane):
                const float x0 = PSWAP(t0);   // half0 receives tgS
                const float x1 = PSWAP(r1);   // half0 receives so

                // c/h update (valid in half0; mirror garbage-but-finite:
                // r's in (0,1], c2 bounded, exp2->inf absorbed by rcp)
                c2 = fmaf(r1, c2, r0 * x0);
                const float Ec = __builtin_amdgcn_exp2f(c2);

                // delayed fc-reduce, second half + store: fills the
                // tanh(c) exp2->rcp window
                p += __int_as_float(__builtin_amdgcn_update_dpp(0, __float_as_int(p), ROR(2), 0xF, 0xF, true));
                p += __int_as_float(__builtin_amdgcn_update_dpp(0, __float_as_int(p), ROR(1), 0xF, 0xF, true));
                if (j == 0 && half == 0) *(float*)((char*)outp + offPrev) = p + fcb;

                const float rc = __builtin_amdgcn_rcpf(1.0f + Ec);
                const float m2 = -2.0f * x1;
                hn = fmaf(m2, rc, x1);

                // refresh half1's h with half0's real value
                const float ph = PSWAP(hn);
                hn = (half == 0) ? hn : ph;
                hbits = __float_as_int(hn);

                // stage this step's output partial + offset
                pPend   = hn * fcwj;
                offPrev = (unsigned)(tc + t4 + u) << 14;   // t * NB * 4B
            }
        }
    }

    // epilogue: flush the final pending output (t = 511)
    {
        float p = pPend;
        p += __int_as_float(__builtin_amdgcn_update_dpp(0, __float_as_int(p), ROR(8), 0xF, 0xF, true));
        p += __int_as_float(__builtin_amdgcn_update_dpp(0, __float_as_int(p), ROR(4), 0xF, 0xF, true));
        p += __int_as_float(__builtin_amdgcn_update_dpp(0, __float_as_int(p), ROR(2), 0xF, 0xF, true));
        p += __int_as_float(__builtin_amdgcn_update_dpp(0, __float_as_int(p), ROR(1), 0xF, 0xF, true));
        if (j == 0 && half == 0) *(float*)((char*)outp + offPrev) = p + fcb;
    }
}

extern "C" void kernel_launch(void* const* d_in, const int* in_sizes, int n_in,
                              void* d_out, int out_size, void* d_ws, size_t ws_size,
                              hipStream_t stream) {
    const float* X    = (const float*)d_in[0];
    const float* W_ih = (const float*)d_in[1];
    const float* W_hh = (const float*)d_in[2];
    const float* b_ih = (const float*)d_in[3];
    const float* b_hh = (const float*)d_in[4];
    const float* fc_w = (const float*)d_in[5];
    const float* fc_b = (const float*)d_in[6];
    float* out = (float*)d_out;

    const int grid = NB / RPW;   // 2048 single-wave blocks: 2 waves/SIMD
    lstm_fused<<<grid, 64, 0, stream>>>(X, W_ih, W_hh, b_ih, b_hh, fc_w, fc_b, out);
}

// Round 10
// 176.146 us; speedup vs baseline: 1.2923x; 1.2923x over previous
//
#include <hip/hip_runtime.h>

// LSTM: T=512, B=4096, IN=1, H=12.
// R20 = EXACT RESTORE of R12 (session best: 122.5 us measured). The
// session's full map, for the record:
//   R12 (this): 122.5us = 574 cyc/step; issue 293, stall 281.
//   R17 = R12+waves_per_eu(1,1)+rcp-pair: 123.6 (residency fix applied,
//        VGPR 56->132, NO effect -> reload theory dead; rcp-pair a wash).
//   R11-line (DPP ror-gather): 130.4-133.6 (issue-bound ~380).
//   2-wave splits: R13 142 (LDS marriage), R15 167 (ds_swizzle),
//        R19 181 (permlane32_swap) - all chain/issue-poisoned.
// Accounting identity proven by R13/R15/R19: wall/SIMD/step =
// max(sum of per-wave issue, single-chain latency), and cells/SIMD is
// pinned at 4 (4096 cells / 1024 SIMDs). In THIS structure every
// instruction already serves all 4 cells (issue/cell = 73 cyc; any wave
// split raises it: R15 137, R19 165). Issue floor audit: trans 10x16 +
// matvec/fc ~90 + DS/loop ~40 = ~290 vs measured 293 -> AT the floor.
// Stall 281 = LDS h round-trip (~150, filler-limited: total filler
// (fc ~30 + x-init ~10) < windows (~200)) + trans tails (~130,
// unfillable at 1 wave). Structural floor ~117us; this kernel is
// within ~4% of it.
//
// Structure:
//  - one cell per 16-lane row (j = lane&15; lanes 12..15 finite clones
//    dumping to unread slots), 4 cells/wave, 1024 single-wave blocks =
//    1 wave/SIMD on all 1024 SIMDs.
//  - h exchange via LDS: hn -> ds_write_b32 slot j (rows on stride-20,
//    ~2-way write alias = benign), read back 3x broadcast ds_read_b128.
//  - in-lane pairwise matvec: per gate, packed init (x-proj + bias via
//    (wx,0),(b,0) pairs) + 6 pk_fma over (h[2k],h[2k+1]) pairs straight
//    from the b128 subregisters. No cross-lane ops in the matvec.
//  - fc dot in-lane (init carries fc_b; 6 pkfma + hadd), DELAYED one
//    step: it consumes the h_{t-1} broadcast and fills the exp2->rcp
//    stall windows. Fake t=0 store aliases out[0][cell], overwritten by
//    the real t=0 store next iteration (same lane+address, program
//    order); epilogue flushes t=511.
//  - pre-scaled gates (sigmoid -log2e, tanh-g +2log2e): activations are
//    rcp(1+exp2(g)); cell state carried pre-scaled c2 = 2log2e*c.
//  - X staged per 64-step chunk to LDS transposed+padded (XPAD=68,
//    conflict-free), global prefetch one chunk ahead; xq ds_read_b128
//    once per 4 steps, one group ahead.
//  - launch_bounds(64,1): no spills.

#define TT    512
#define NB    4096
#define HH    12
#define RPW   4      // cells per wave
#define CHUNK 64     // X staging chunk; TT % CHUNK == 0
#define XPAD  68     // padded x row stride (floats): breaks bank aliasing
#define HSTR  20     // h row stride (floats): 80B, 16B-aligned, banks spread

typedef float v2f __attribute__((ext_vector_type(2)));
typedef float v4f __attribute__((ext_vector_type(4)));

static __device__ __forceinline__ v2f pkfma(v2f a, v2f b, v2f c) {
#if __has_builtin(__builtin_elementwise_fma)
    return __builtin_elementwise_fma(a, b, c);
#else
    v2f r; r.x = fmaf(a.x, b.x, c.x); r.y = fmaf(a.y, b.y, c.y); return r;
#endif
}

#define SNEG   (-1.44269504088896340736f)   // sigmoid pre-scale: -log2(e)
#define SPOS   ( 2.88539008177792681472f)   // tanh pre-scale: +2*log2(e)
#define M2SPOS (-5.77078016355585362944f)   // -2*SPOS

__global__ __launch_bounds__(64, 1)
void lstm_fused(const float* __restrict__ X,
                const float* __restrict__ W_ih,
                const float* __restrict__ W_hh,
                const float* __restrict__ b_ih,
                const float* __restrict__ b_hh,
                const float* __restrict__ fc_w,
                const float* __restrict__ fc_b,
                float* __restrict__ out)
{
    __shared__ __align__(16) float xchunk[RPW][XPAD]; // [row][time], padded
    __shared__ __align__(16) float hsh[RPW][HSTR];    // [row][h-slot]

    const int lane = threadIdx.x;        // 0..63
    const int row  = lane >> 4;          // 0..3  : cell slot
    const int j    = lane & 15;          // 0..11 real, 12..15 clone lanes
    const int cellbase = blockIdx.x * RPW;
    const int cell = cellbase + row;     // grid sized so cell < NB always

    const int jc = (j < HH) ? j : (HH - 1);   // clamp clone lanes (finite)

    // ---- in-lane pairwise weights: per gate, 6 v2f of (W[s],W[s+1]),
    // pre-scaled (i,f,o: SNEG; g: SPOS). Rows of W_hh are contiguous [12].
    v2f wI[6], wF[6], wG[6], wO[6], fcv[6];
    #pragma unroll
    for (int k = 0; k < 6; ++k) {
        const float* r0 = W_hh + (0 * HH + jc) * HH + 2 * k;
        const float* r1 = W_hh + (1 * HH + jc) * HH + 2 * k;
        const float* r2 = W_hh + (2 * HH + jc) * HH + 2 * k;
        const float* r3 = W_hh + (3 * HH + jc) * HH + 2 * k;
        wI[k].x = SNEG * r0[0];  wI[k].y = SNEG * r0[1];
        wF[k].x = SNEG * r1[0];  wF[k].y = SNEG * r1[1];
        wG[k].x = SPOS * r2[0];  wG[k].y = SPOS * r2[1];
        wO[k].x = SNEG * r3[0];  wO[k].y = SNEG * r3[1];
        fcv[k].x = fc_w[2 * k];  fcv[k].y = fc_w[2 * k + 1];
    }
    // head constants: init acc_g = pkfma((x,x), (wx_g,0), (b_g,0))
    v2f wxI, wxF, wxG, wxO, bI, bF, bG, bO, bFC;
    wxI.x = SNEG * W_ih[0 * HH + jc];  wxI.y = 0.0f;
    wxF.x = SNEG * W_ih[1 * HH + jc];  wxF.y = 0.0f;
    wxG.x = SPOS * W_ih[2 * HH + jc];  wxG.y = 0.0f;
    wxO.x = SNEG * W_ih[3 * HH + jc];  wxO.y = 0.0f;
    bI.x = SNEG * (b_ih[0 * HH + jc] + b_hh[0 * HH + jc]);  bI.y = 0.0f;
    bF.x = SNEG * (b_ih[1 * HH + jc] + b_hh[1 * HH + jc]);  bF.y = 0.0f;
    bG.x = SPOS * (b_ih[2 * HH + jc] + b_hh[2 * HH + jc]);  bG.y = 0.0f;
    bO.x = SNEG * (b_ih[3 * HH + jc] + b_hh[3 * HH + jc]);  bO.y = 0.0f;
    bFC.x = fc_b[0];  bFC.y = 0.0f;     // fc bias folded into fc init

    float c2 = 0.0f;     // pre-scaled cell state: SPOS * c[cell][j]
    float hn = 0.0f;     // my h element h[cell][j]  (h0 = 0)

    float* const hrow = &hsh[row][0];
    // every lane has a distinct write slot; clones dump to 12..15 (never read)
    const int wslot = j;

    // delayed-output state (R11 trick): iteration t computes fc(h_{t-1});
    // first (fake) store aliases out[0][cell], overwritten next iteration.
    unsigned offPrev = 0;
    float* const outp = out + cell;

    // initial h0 = 0 into LDS (same-wave DS in-order vs later reads)
    hrow[wslot] = 0.0f;
    __builtin_amdgcn_wave_barrier();

    // prefetch chunk 0 of X into registers
    float4 gq = *(const float4*)(X + (size_t)lane * NB + cellbase);

    for (int tc = 0; tc < TT; tc += CHUNK) {
        // stage prefetched chunk to LDS (transposed/padded), prefetch next
        xchunk[0][lane] = gq.x;
        xchunk[1][lane] = gq.y;
        xchunk[2][lane] = gq.z;
        xchunk[3][lane] = gq.w;
        if (tc + CHUNK < TT)
            gq = *(const float4*)(X + (size_t)(tc + CHUNK + lane) * NB + cellbase);

        float4 xq_next = *(const float4*)&xchunk[row][0];

        for (int t4 = 0; t4 < CHUNK; t4 += 4) {
            const float4 xq = xq_next;                       // group t4
            const int nx = (t4 + 4 < CHUNK) ? (t4 + 4) : t4; // clamp tail
            xq_next = *(const float4*)&xchunk[row][nx];      // prefetch next
            const float xs[4] = {xq.x, xq.y, xq.z, xq.w};

            #pragma unroll
            for (int u = 0; u < 4; ++u) {
                // broadcast-read the row's h_{t-1} (3x ds_read_b128,
                // disjoint banks across rows by stride-20 layout)
                const v4f ha = *(const v4f*)&hrow[0];
                const v4f hb = *(const v4f*)&hrow[4];
                const v4f hc = *(const v4f*)&hrow[8];
                v2f hp0; hp0.x = ha.x; hp0.y = ha.y;
                v2f hp1; hp1.x = ha.z; hp1.y = ha.w;
                v2f hp2; hp2.x = hb.x; hp2.y = hb.y;
                v2f hp3; hp3.x = hb.z; hp3.y = hb.w;
                v2f hp4; hp4.x = hc.x; hp4.y = hc.y;
                v2f hp5; hp5.x = hc.z; hp5.y = hc.w;

                // gate chains: packed init (x-proj + bias), then 6 pair fmas
                v2f xvv; xvv.x = xs[u]; xvv.y = xs[u];
                v2f aI = pkfma(xvv, wxI, bI);
                v2f aF = pkfma(xvv, wxF, bF);
                v2f aG = pkfma(xvv, wxG, bG);
                v2f aO = pkfma(xvv, wxO, bO);
                // fc of h_{t-1} (delayed output), bias pre-folded: pure
                // filler for the trans windows below
                v2f pf = pkfma(fcv[0], hp0, bFC);
                aI = pkfma(wI[0], hp0, aI);  aF = pkfma(wF[0], hp0, aF);
                aG = pkfma(wG[0], hp0, aG);  aO = pkfma(wO[0], hp0, aO);
                aI = pkfma(wI[1], hp1, aI);  aF = pkfma(wF[1], hp1, aF);
                aG = pkfma(wG[1], hp1, aG);  aO = pkfma(wO[1], hp1, aO);
                pf = pkfma(fcv[1], hp1, pf);
                aI = pkfma(wI[2], hp2, aI);  aF = pkfma(wF[2], hp2, aF);
                aG = pkfma(wG[2], hp2, aG);  aO = pkfma(wO[2], hp2, aO);
                pf = pkfma(fcv[2], hp2, pf);
                aI = pkfma(wI[3], hp3, aI);  aF = pkfma(wF[3], hp3, aF);
                aG = pkfma(wG[3], hp3, aG);  aO = pkfma(wO[3], hp3, aO);
                pf = pkfma(fcv[3], hp3, pf);
                aI = pkfma(wI[4], hp4, aI);  aF = pkfma(wF[4], hp4, aF);
                aG = pkfma(wG[4], hp4, aG);  aO = pkfma(wO[4], hp4, aO);
                pf = pkfma(fcv[4], hp4, pf);
                aI = pkfma(wI[5], hp5, aI);  aF = pkfma(wF[5], hp5, aF);
                aG = pkfma(wG[5], hp5, aG);  aO = pkfma(wO[5], hp5, aO);
                pf = pkfma(fcv[5], hp5, pf);

                const float gi = aI.x + aI.y;
                const float gf = aF.x + aF.y;
                const float gg = aG.x + aG.y;
                const float go = aO.x + aO.y;

                const float Ei = __builtin_amdgcn_exp2f(gi);
                const float Ef = __builtin_amdgcn_exp2f(gf);
                const float Eg = __builtin_amdgcn_exp2f(gg);
                const float Eo = __builtin_amdgcn_exp2f(go);

                // delayed output store: fills the gate exp2->rcp window
                const float p = pf.x + pf.y;
                if (j == 0) *(float*)((char*)outp + offPrev) = p;

                const float si = __builtin_amdgcn_rcpf(1.0f + Ei);
                const float sf = __builtin_amdgcn_rcpf(1.0f + Ef);
                const float rg = __builtin_amdgcn_rcpf(1.0f + Eg);
                const float so = __builtin_amdgcn_rcpf(1.0f + Eo);

                // pre-scaled cell update
                const float tgS = fmaf(M2SPOS, rg, SPOS);
                c2 = fmaf(sf, c2, si * tgS);
                const float Ec = __builtin_amdgcn_exp2f(c2);   // exp2(SPOS*c)
                const float rc = __builtin_amdgcn_rcpf(1.0f + Ec);
                const float m2so = -2.0f * so;
                hn = fmaf(m2so, rc, so);

                // publish h_t for next iteration's broadcast read
                hrow[wslot] = hn;
                __builtin_amdgcn_wave_barrier();

                offPrev = (unsigned)(tc + t4 + u) << 14;   // t * NB * 4B
            }
        }
    }

    // epilogue: fc(h_511) -> out[511]
    {
        const v4f ha = *(const v4f*)&hrow[0];
        const v4f hb = *(const v4f*)&hrow[4];
        const v4f hc = *(const v4f*)&hrow[8];
        v2f hp0; hp0.x = ha.x; hp0.y = ha.y;
        v2f hp1; hp1.x = ha.z; hp1.y = ha.w;
        v2f hp2; hp2.x = hb.x; hp2.y = hb.y;
        v2f hp3; hp3.x = hb.z; hp3.y = hb.w;
        v2f hp4; hp4.x = hc.x; hp4.y = hc.y;
        v2f hp5; hp5.x = hc.z; hp5.y = hc.w;
        v2f pf = pkfma(fcv[0], hp0, bFC);
        pf = pkfma(fcv[1], hp1, pf);
        pf = pkfma(fcv[2], hp2, pf);
        pf = pkfma(fcv[3], hp3, pf);
        pf = pkfma(fcv[4], hp4, pf);
        pf = pkfma(fcv[5], hp5, pf);
        const float p = pf.x + pf.y;
        if (j == 0) *(float*)((char*)outp + offPrev) = p;
    }
}

extern "C" void kernel_launch(void* const* d_in, const int* in_sizes, int n_in,
                              void* d_out, int out_size, void* d_ws, size_t ws_size,
                              hipStream_t stream) {
    const float* X    = (const float*)d_in[0];
    const float* W_ih = (const float*)d_in[1];
    const float* W_hh = (const float*)d_in[2];
    const float* b_ih = (const float*)d_in[3];
    const float* b_hh = (const float*)d_in[4];
    const float* fc_w = (const float*)d_in[5];
    const float* fc_b = (const float*)d_in[6];
    float* out = (float*)d_out;

    const int grid = NB / RPW;   // 1024 single-wave blocks: every SIMD busy
    lstm_fused<<<grid, 64, 0, stream>>>(X, W_ih, W_hh, b_ih, b_hh, fc_w, fc_b, out);
}